// Round 3
// baseline (4175.815 us; speedup 1.0000x reference)
//
#include <hip/hip_runtime.h>

#define B_SZ 2
#define L_SEQ 2048
#define DM 768
#define DI 1536
#define DS 16
#define NROWS (B_SZ * L_SEQ)   // 4096

__device__ __forceinline__ float softplusf(float x) {
    return (x > 20.f) ? x : log1pf(expf(x));
}

__device__ __forceinline__ float quantw(float w, float s, float inv_s) {
    float t = fminf(fmaxf(w * inv_s, -1.f), 1.f);
    return rintf(t) * s;
}

// ---- block reduction (blockDim.x multiple of 64, <=512) ----
__device__ float blockReduceSum(float v, float* sh) {
    int tid = threadIdx.x;
    int lane = tid & 63, w = tid >> 6;
#pragma unroll
    for (int off = 32; off; off >>= 1) v += __shfl_xor(v, off);
    if (lane == 0) sh[w] = v;
    __syncthreads();
    int nw = blockDim.x >> 6;
    float t = (tid < nw) ? sh[tid] : 0.f;
    if (w == 0) {
#pragma unroll
        for (int off = 4; off; off >>= 1) t += __shfl_xor(t, off);
    }
    if (tid == 0) sh[0] = t;
    __syncthreads();
    float r = sh[0];
    __syncthreads();
    return r;
}

// ---- fused rmsnorm(x,norm_w) then rmsnorm(.,inp_norm_w) -> xn fp32 ----
__global__ void rmsnorm2_kernel(const float* __restrict__ x, const float* __restrict__ w1,
                                const float* __restrict__ w2, float* __restrict__ xn) {
    __shared__ float sh[8];
    int row = blockIdx.x;
    const float* xr = x + (long)row * DM;
    float v[3];
    float ss = 0.f;
#pragma unroll
    for (int i = 0; i < 3; i++) {
        v[i] = xr[threadIdx.x + 256 * i];
        ss += v[i] * v[i];
    }
    ss = blockReduceSum(ss, sh);
    float r1 = rsqrtf(ss / DM + 1e-6f);
    float h[3];
    float ss2 = 0.f;
#pragma unroll
    for (int i = 0; i < 3; i++) {
        h[i] = v[i] * r1 * w1[threadIdx.x + 256 * i];
        ss2 += h[i] * h[i];
    }
    ss2 = blockReduceSum(ss2, sh);
    float r2 = rsqrtf(ss2 / DM + 1e-6f);
#pragma unroll
    for (int i = 0; i < 3; i++)
        xn[(long)row * DM + threadIdx.x + 256 * i] = h[i] * r2 * w2[threadIdx.x + 256 * i];
}

// ---- |W| partial sums, one value per block (deterministic within-block order) ----
__global__ void abssum_partial_kernel(const float* __restrict__ w, int n,
                                      float* __restrict__ partials) {
    __shared__ float sh[8];
    float s = 0.f;
    for (int i = blockIdx.x * blockDim.x + threadIdx.x; i < n; i += gridDim.x * blockDim.x)
        s += fabsf(w[i]);
    s = blockReduceSum(s, sh);
    if (threadIdx.x == 0) partials[blockIdx.x] = s;
}

// ---- reduce 1024 partials in fixed order (single block of 512) ----
__global__ void reduce_partials_kernel(const float* __restrict__ partials,
                                       float* __restrict__ out) {
    __shared__ float sh[8];
    float s = partials[threadIdx.x] + partials[threadIdx.x + 512];
    s = blockReduceSum(s, sh);
    if (threadIdx.x == 0) out[0] = s;
}

// ---- C[M,N] = A[M,K] @ quant(B[N,K])^T, fp32, 16x16 LDS tiles ----
__global__ void matmul_tt_kernel(const float* __restrict__ A, const float* __restrict__ Bm,
                                 float* __restrict__ C, int M, int N, int K,
                                 const float* __restrict__ scal, float invn) {
    __shared__ float As[16][17], Bs[16][17];
    float s = fmaxf(scal[0] * invn, 1e-5f);
    float inv_s = 1.f / s;
    int tx = threadIdx.x, ty = threadIdx.y;
    int m0 = blockIdx.y * 16, n0 = blockIdx.x * 16;
    float acc = 0.f;
    for (int k0 = 0; k0 < K; k0 += 16) {
        As[ty][tx] = A[(long)(m0 + ty) * K + k0 + tx];
        Bs[ty][tx] = quantw(Bm[(long)(n0 + ty) * K + k0 + tx], s, inv_s);
        __syncthreads();
#pragma unroll
        for (int k = 0; k < 16; k++) acc = fmaf(As[ty][k], Bs[tx][k], acc);
        __syncthreads();
    }
    C[(long)(m0 + ty) * N + n0 + tx] = acc;
}

// ---- same but epilogue: + residual, write float out ----
__global__ void matmul_out_kernel(const float* __restrict__ A, const float* __restrict__ Bm,
                                  const float* __restrict__ resid, float* __restrict__ out,
                                  int M, int N, int K,
                                  const float* __restrict__ scal, float invn) {
    __shared__ float As[16][17], Bs[16][17];
    float s = fmaxf(scal[0] * invn, 1e-5f);
    float inv_s = 1.f / s;
    int tx = threadIdx.x, ty = threadIdx.y;
    int m0 = blockIdx.y * 16, n0 = blockIdx.x * 16;
    float acc = 0.f;
    for (int k0 = 0; k0 < K; k0 += 16) {
        As[ty][tx] = A[(long)(m0 + ty) * K + k0 + tx];
        Bs[ty][tx] = quantw(Bm[(long)(n0 + ty) * K + k0 + tx], s, inv_s);
        __syncthreads();
#pragma unroll
        for (int k = 0; k < 16; k++) acc = fmaf(As[ty][k], Bs[tx][k], acc);
        __syncthreads();
    }
    long idx = (long)(m0 + ty) * N + n0 + tx;
    out[idx] = acc + resid[idx];
}

// ---- causal depthwise conv (k=4) + bias + silu ----
__global__ void conv_silu_kernel(const float* __restrict__ xz, const float* __restrict__ cw,
                                 const float* __restrict__ cb, float* __restrict__ xc) {
    int id = blockIdx.x * blockDim.x + threadIdx.x;
    if (id >= NROWS * DI) return;
    int c = id % DI;
    int rl = id / DI;       // b*L + l
    int l = rl % L_SEQ;
    float acc = cb[c];
#pragma unroll
    for (int k = 0; k < 4; k++) {
        int ls = l - 3 + k;
        if (ls >= 0) acc = fmaf(xz[(long)(rl - 3 + k) * (2 * DI) + c], cw[c * 4 + k], acc);
    }
    xc[id] = acc / (1.f + expf(-acc));   // silu
}

// ---- dbc[row, 0..32] = xc[row,:] @ xproj_W^T ; one wave per row ----
__global__ void xproj_kernel(const float* __restrict__ xc, const float* __restrict__ xw,
                             float* __restrict__ dbc) {
    int row = blockIdx.x;
    int lane = threadIdx.x;  // 64
    float xr[24];
    const float* xrow = xc + (long)row * DI;
#pragma unroll
    for (int j = 0; j < 24; j++) xr[j] = xrow[lane + 64 * j];
    for (int o = 0; o < 33; o++) {
        const float* wr = xw + o * DI;
        float a = 0.f;
#pragma unroll
        for (int j = 0; j < 24; j++) a = fmaf(xr[j], wr[lane + 64 * j], a);
#pragma unroll
        for (int off = 32; off; off >>= 1) a += __shfl_xor(a, off);
        if (lane == 0) dbc[(long)row * 33 + o] = a;
    }
}

// ---- selective scan: 16 channels x 16 states per block; fused +x*D and *silu(z) ----
__global__ void scan_kernel(const float* __restrict__ dbc, const float* __restrict__ xc,
                            const float* __restrict__ xz, float* __restrict__ yout,
                            const float* __restrict__ A_log, const float* __restrict__ dt_W,
                            const float* __restrict__ dt_b, const float* __restrict__ Dv) {
    int n = threadIdx.x & 15;
    int ci = threadIdx.x >> 4;
    int b = blockIdx.x / (DI / 16);
    int c = (blockIdx.x % (DI / 16)) * 16 + ci;
    float A = -expf(A_log[c * DS + n]);
    float dtw = dt_W[c];
    float dtb = dt_b[c];
    float Dc = Dv[c];
    float h = 0.f;
    for (int l = 0; l < L_SEQ; l++) {
        int row = b * L_SEQ + l;
        const float* dr = dbc + (long)row * 33;
        float dt = softplusf(fmaf(dr[0], dtw, dtb));
        float Bn = dr[1 + n];
        float Cn = dr[17 + n];
        float xv = xc[(long)row * DI + c];
        h = fmaf(expf(dt * A), h, dt * xv * Bn);
        float p = h * Cn;
        p += __shfl_xor(p, 1);
        p += __shfl_xor(p, 2);
        p += __shfl_xor(p, 4);
        p += __shfl_xor(p, 8);
        if (n == 0) {
            float zv = xz[(long)row * 2 * DI + DI + c];
            float y = p + xv * Dc;
            yout[(long)row * 2 * DI + c] = y * (zv / (1.f + expf(-zv)));
        }
    }
}

// ---- rmsnorm over y (stride-2*DI rows) -> yn fp32 ----
__global__ void rmsnorm_y_kernel(const float* __restrict__ xz, const float* __restrict__ w,
                                 float* __restrict__ yn) {
    __shared__ float sh[8];
    int row = blockIdx.x;
    const float* yr = xz + (long)row * 2 * DI;
    float v[6];
    float ss = 0.f;
#pragma unroll
    for (int i = 0; i < 6; i++) {
        v[i] = yr[threadIdx.x + 256 * i];
        ss += v[i] * v[i];
    }
    ss = blockReduceSum(ss, sh);
    float r = rsqrtf(ss / DI + 1e-6f);
#pragma unroll
    for (int i = 0; i < 6; i++)
        yn[(long)row * DI + threadIdx.x + 256 * i] = v[i] * r * w[threadIdx.x + 256 * i];
}

extern "C" void kernel_launch(void* const* d_in, const int* in_sizes, int n_in,
                              void* d_out, int out_size, void* d_ws, size_t ws_size,
                              hipStream_t stream) {
    const float* x          = (const float*)d_in[0];
    const float* norm_w     = (const float*)d_in[1];
    const float* inp_norm_w = (const float*)d_in[2];
    const float* inp_W      = (const float*)d_in[3];
    const float* conv_w     = (const float*)d_in[4];
    const float* conv_b     = (const float*)d_in[5];
    const float* xproj_W    = (const float*)d_in[6];
    const float* dt_W       = (const float*)d_in[7];
    const float* dt_b       = (const float*)d_in[8];
    const float* A_log      = (const float*)d_in[9];
    const float* Dv         = (const float*)d_in[10];
    const float* out_norm_w = (const float*)d_in[11];
    const float* out_W      = (const float*)d_in[12];
    float* out = (float*)d_out;

    float* ws  = (float*)d_ws;
    float* xz  = ws;                         // NROWS*2*DI (x_path half reused for scan out)
    float* xc  = xz + (long)NROWS * 2 * DI;  // NROWS*DI (conv out; later yn). xn aliases here.
    float* xn  = xc;                         // NROWS*DM (dead before xc is written)
    float* dbc = xc + (long)NROWS * DI;      // NROWS*33
    float* scal = dbc + (long)NROWS * 33;    // [0]=sum|inp_W|, [1]=sum|out_W|
    float* part = scal + 2;                  // 2*1024 partials

    rmsnorm2_kernel<<<NROWS, 256, 0, stream>>>(x, norm_w, inp_norm_w, xn);
    abssum_partial_kernel<<<1024, 256, 0, stream>>>(inp_W, 2 * DI * DM, part);
    reduce_partials_kernel<<<1, 512, 0, stream>>>(part, scal);
    abssum_partial_kernel<<<1024, 256, 0, stream>>>(out_W, DM * DI, part + 1024);
    reduce_partials_kernel<<<1, 512, 0, stream>>>(part + 1024, scal + 1);

    dim3 t16(16, 16);
    matmul_tt_kernel<<<dim3(2 * DI / 16, NROWS / 16), t16, 0, stream>>>(
        xn, inp_W, xz, NROWS, 2 * DI, DM, scal, 1.f / (2 * DI * DM));
    conv_silu_kernel<<<(NROWS * DI + 255) / 256, 256, 0, stream>>>(xz, conv_w, conv_b, xc);
    xproj_kernel<<<NROWS, 64, 0, stream>>>(xc, xproj_W, dbc);
    scan_kernel<<<B_SZ * (DI / 16), 256, 0, stream>>>(dbc, xc, xz, xz, A_log, dt_W, dt_b, Dv);
    rmsnorm_y_kernel<<<NROWS, 256, 0, stream>>>(xz, out_norm_w, xc);
    matmul_out_kernel<<<dim3(DM / 16, NROWS / 16), t16, 0, stream>>>(
        xc, out_W, x, out, NROWS, DM, DI, scal + 1, 1.f / (DM * DI));
}

// Round 4
// 1871.866 us; speedup vs baseline: 2.2308x; 2.2308x over previous
//
#include <hip/hip_runtime.h>

#define B_SZ 2
#define L_SEQ 2048
#define DM 768
#define DI 1536
#define DS 16
#define NROWS (B_SZ * L_SEQ)   // 4096
#define CHT 64                 // scan timestep tile

__device__ __forceinline__ float softplusf(float x) {
    return (x > 20.f) ? x : log1pf(expf(x));
}

__device__ __forceinline__ float quantw(float w, float s, float inv_s) {
    float t = fminf(fmaxf(w * inv_s, -1.f), 1.f);
    return rintf(t) * s;
}

// ---- block reduction (blockDim.x multiple of 64, <=512) ----
__device__ float blockReduceSum(float v, float* sh) {
    int tid = threadIdx.x;
    int lane = tid & 63, w = tid >> 6;
#pragma unroll
    for (int off = 32; off; off >>= 1) v += __shfl_xor(v, off);
    if (lane == 0) sh[w] = v;
    __syncthreads();
    int nw = blockDim.x >> 6;
    float t = (tid < nw) ? sh[tid] : 0.f;
    if (w == 0) {
#pragma unroll
        for (int off = 4; off; off >>= 1) t += __shfl_xor(t, off);
    }
    if (tid == 0) sh[0] = t;
    __syncthreads();
    float r = sh[0];
    __syncthreads();
    return r;
}

// ---- fused rmsnorm(x,norm_w) then rmsnorm(.,inp_norm_w) -> xn fp32 ----
__global__ void rmsnorm2_kernel(const float* __restrict__ x, const float* __restrict__ w1,
                                const float* __restrict__ w2, float* __restrict__ xn) {
    __shared__ float sh[8];
    int row = blockIdx.x;
    const float* xr = x + (long)row * DM;
    float v[3];
    float ss = 0.f;
#pragma unroll
    for (int i = 0; i < 3; i++) {
        v[i] = xr[threadIdx.x + 256 * i];
        ss += v[i] * v[i];
    }
    ss = blockReduceSum(ss, sh);
    float r1 = rsqrtf(ss / DM + 1e-6f);
    float h[3];
    float ss2 = 0.f;
#pragma unroll
    for (int i = 0; i < 3; i++) {
        h[i] = v[i] * r1 * w1[threadIdx.x + 256 * i];
        ss2 += h[i] * h[i];
    }
    ss2 = blockReduceSum(ss2, sh);
    float r2 = rsqrtf(ss2 / DM + 1e-6f);
#pragma unroll
    for (int i = 0; i < 3; i++)
        xn[(long)row * DM + threadIdx.x + 256 * i] = h[i] * r2 * w2[threadIdx.x + 256 * i];
}

// ---- |W| partial sums, one value per block ----
__global__ void abssum_partial_kernel(const float* __restrict__ w, int n,
                                      float* __restrict__ partials) {
    __shared__ float sh[8];
    float s = 0.f;
    for (int i = blockIdx.x * blockDim.x + threadIdx.x; i < n; i += gridDim.x * blockDim.x)
        s += fabsf(w[i]);
    s = blockReduceSum(s, sh);
    if (threadIdx.x == 0) partials[blockIdx.x] = s;
}

// ---- reduce 1024 partials in fixed order ----
__global__ void reduce_partials_kernel(const float* __restrict__ partials,
                                       float* __restrict__ out) {
    __shared__ float sh[8];
    float s = partials[threadIdx.x] + partials[threadIdx.x + 512];
    s = blockReduceSum(s, sh);
    if (threadIdx.x == 0) out[0] = s;
}

// ---- C[M,N] = A[M,K] @ quant(B[N,K])^T (+resid), 128x128 tile, 8x8/thread ----
__global__ __launch_bounds__(256)
void matmul_big_kernel(const float* __restrict__ A, const float* __restrict__ Bm,
                       const float* __restrict__ resid, float* __restrict__ C,
                       int M, int N, int K,
                       const float* __restrict__ scal, float invn) {
    __shared__ float As[16][132], Bs[16][132];
    float s = fmaxf(scal[0] * invn, 1e-5f);
    float inv_s = 1.f / s;
    int tid = threadIdx.x;
    int tx = tid & 15, ty = tid >> 4;
    int m0 = blockIdx.y * 128, n0 = blockIdx.x * 128;
    int ar = tid >> 1;            // 0..127
    int akk = (tid & 1) * 8;      // 0 or 8
    const float* apb = A + (long)(m0 + ar) * K + akk;
    const float* bpb = Bm + (long)(n0 + ar) * K + akk;
    float acc[8][8] = {};
    for (int k0 = 0; k0 < K; k0 += 16) {
        float4 a0 = *(const float4*)(apb + k0);
        float4 a1 = *(const float4*)(apb + k0 + 4);
        float4 b0 = *(const float4*)(bpb + k0);
        float4 b1 = *(const float4*)(bpb + k0 + 4);
        As[akk + 0][ar] = a0.x; As[akk + 1][ar] = a0.y;
        As[akk + 2][ar] = a0.z; As[akk + 3][ar] = a0.w;
        As[akk + 4][ar] = a1.x; As[akk + 5][ar] = a1.y;
        As[akk + 6][ar] = a1.z; As[akk + 7][ar] = a1.w;
        Bs[akk + 0][ar] = quantw(b0.x, s, inv_s); Bs[akk + 1][ar] = quantw(b0.y, s, inv_s);
        Bs[akk + 2][ar] = quantw(b0.z, s, inv_s); Bs[akk + 3][ar] = quantw(b0.w, s, inv_s);
        Bs[akk + 4][ar] = quantw(b1.x, s, inv_s); Bs[akk + 5][ar] = quantw(b1.y, s, inv_s);
        Bs[akk + 6][ar] = quantw(b1.z, s, inv_s); Bs[akk + 7][ar] = quantw(b1.w, s, inv_s);
        __syncthreads();
#pragma unroll
        for (int k = 0; k < 16; k++) {
            float av[8], bv[8];
            *(float4*)(av)     = *(const float4*)&As[k][ty * 8];
            *(float4*)(av + 4) = *(const float4*)&As[k][ty * 8 + 4];
            *(float4*)(bv)     = *(const float4*)&Bs[k][tx * 4];
            *(float4*)(bv + 4) = *(const float4*)&Bs[k][64 + tx * 4];
#pragma unroll
            for (int i = 0; i < 8; i++)
#pragma unroll
                for (int j = 0; j < 8; j++)
                    acc[i][j] = fmaf(av[i], bv[j], acc[i][j]);
        }
        __syncthreads();
    }
#pragma unroll
    for (int i = 0; i < 8; i++) {
        long m = m0 + ty * 8 + i;
#pragma unroll
        for (int half = 0; half < 2; half++) {
            long idx = m * N + n0 + half * 64 + tx * 4;
            float4 v;
            v.x = acc[i][half * 4 + 0]; v.y = acc[i][half * 4 + 1];
            v.z = acc[i][half * 4 + 2]; v.w = acc[i][half * 4 + 3];
            if (resid) {
                float4 r4 = *(const float4*)(resid + idx);
                v.x += r4.x; v.y += r4.y; v.z += r4.z; v.w += r4.w;
            }
            *(float4*)(C + idx) = v;
        }
    }
}

// ---- causal depthwise conv (k=4) + bias + silu ----
__global__ void conv_silu_kernel(const float* __restrict__ xz, const float* __restrict__ cw,
                                 const float* __restrict__ cb, float* __restrict__ xc) {
    int id = blockIdx.x * blockDim.x + threadIdx.x;
    if (id >= NROWS * DI) return;
    int c = id % DI;
    int rl = id / DI;       // b*L + l
    int l = rl % L_SEQ;
    float acc = cb[c];
#pragma unroll
    for (int k = 0; k < 4; k++) {
        int ls = l - 3 + k;
        if (ls >= 0) acc = fmaf(xz[(long)(rl - 3 + k) * (2 * DI) + c], cw[c * 4 + k], acc);
    }
    xc[id] = acc / (1.f + expf(-acc));   // silu
}

// ---- dbc[row, 0..32] = xc[row,:] @ xproj_W^T ; one wave per row ----
__global__ void xproj_kernel(const float* __restrict__ xc, const float* __restrict__ xw,
                             float* __restrict__ dbc) {
    int row = blockIdx.x;
    int lane = threadIdx.x;  // 64
    float xr[24];
    const float* xrow = xc + (long)row * DI;
#pragma unroll
    for (int j = 0; j < 24; j++) xr[j] = xrow[lane + 64 * j];
    for (int o = 0; o < 33; o++) {
        const float* wr = xw + o * DI;
        float a = 0.f;
#pragma unroll
        for (int j = 0; j < 24; j++) a = fmaf(xr[j], wr[lane + 64 * j], a);
#pragma unroll
        for (int off = 32; off; off >>= 1) a += __shfl_xor(a, off);
        if (lane == 0) dbc[(long)row * 33 + o] = a;
    }
}

// ---- selective scan, LDS-tiled double-buffered ----
// block: 256 thr = 16 channels x 16 states; grid: B_SZ * 96
__global__ __launch_bounds__(256)
void scan_kernel(const float* __restrict__ dbc, const float* __restrict__ xc,
                 const float* __restrict__ xz, float* __restrict__ yout,
                 const float* __restrict__ A_log, const float* __restrict__ dt_W,
                 const float* __restrict__ dt_b, const float* __restrict__ Dv) {
    __shared__ float sdt[2][CHT];
    __shared__ float sB[2][CHT][16];
    __shared__ float sC[2][CHT][16];
    __shared__ float sx[2][CHT][16];
    __shared__ float sz[2][CHT][16];
    __shared__ float sy[2][CHT][16];

    int tid = threadIdx.x;
    int n = tid & 15, ci = tid >> 4;
    int b = blockIdx.x / (DI / 16);
    int cg = blockIdx.x % (DI / 16);
    int c = cg * 16 + ci;

    float A   = -expf(A_log[c * DS + n]);
    float dtw = dt_W[c];
    float dtb = dt_b[c];
    float Dc  = Dv[c];

    auto stage = [&](int buf, int t0) {
        long row0 = (long)b * L_SEQ + t0;
        // dbc tile: contiguous 64*33 floats
        for (int idx = tid; idx < CHT * 33; idx += 256) {
            float v = dbc[row0 * 33 + idx];
            int r = idx / 33, j = idx - r * 33;
            if (j == 0)       sdt[buf][r] = v;
            else if (j < 17)  sB[buf][r][j - 1] = v;
            else              sC[buf][r][j - 17] = v;
        }
        // x and z tiles: 64 rows x 16 channels
        for (int idx = tid; idx < CHT * 16; idx += 256) {
            int r = idx >> 4, cc = idx & 15;
            sx[buf][r][cc] = xc[(row0 + r) * DI + cg * 16 + cc];
            sz[buf][r][cc] = xz[(row0 + r) * 2 * DI + DI + cg * 16 + cc];
        }
    };

    stage(0, 0);
    float h = 0.f;
    int buf = 0;
    const int NTILES = L_SEQ / CHT;
    for (int t = 0; t < NTILES; t++) {
        __syncthreads();
        if (t + 1 < NTILES) stage(buf ^ 1, (t + 1) * CHT);
#pragma unroll 4
        for (int r = 0; r < CHT; r++) {
            float dt = softplusf(fmaf(sdt[buf][r], dtw, dtb));
            float xv = sx[buf][r][ci];
            h = fmaf(expf(dt * A), h, dt * xv * sB[buf][r][n]);
            float p = h * sC[buf][r][n];
            p += __shfl_xor(p, 1);
            p += __shfl_xor(p, 2);
            p += __shfl_xor(p, 4);
            p += __shfl_xor(p, 8);
            if (n == 0) {
                float zv = sz[buf][r][ci];
                sy[buf][r][ci] = (p + xv * Dc) * (zv / (1.f + expf(-zv)));
            }
        }
        __syncthreads();
        long row0 = (long)b * L_SEQ + t * CHT;
        for (int idx = tid; idx < CHT * 16; idx += 256) {
            int r = idx >> 4, cc = idx & 15;
            yout[(row0 + r) * 2 * DI + cg * 16 + cc] = sy[buf][r][cc];
        }
        buf ^= 1;
    }
}

// ---- rmsnorm over y (stride-2*DI rows) -> yn fp32 ----
__global__ void rmsnorm_y_kernel(const float* __restrict__ xz, const float* __restrict__ w,
                                 float* __restrict__ yn) {
    __shared__ float sh[8];
    int row = blockIdx.x;
    const float* yr = xz + (long)row * 2 * DI;
    float v[6];
    float ss = 0.f;
#pragma unroll
    for (int i = 0; i < 6; i++) {
        v[i] = yr[threadIdx.x + 256 * i];
        ss += v[i] * v[i];
    }
    ss = blockReduceSum(ss, sh);
    float r = rsqrtf(ss / DI + 1e-6f);
#pragma unroll
    for (int i = 0; i < 6; i++)
        yn[(long)row * DI + threadIdx.x + 256 * i] = v[i] * r * w[threadIdx.x + 256 * i];
}

extern "C" void kernel_launch(void* const* d_in, const int* in_sizes, int n_in,
                              void* d_out, int out_size, void* d_ws, size_t ws_size,
                              hipStream_t stream) {
    const float* x          = (const float*)d_in[0];
    const float* norm_w     = (const float*)d_in[1];
    const float* inp_norm_w = (const float*)d_in[2];
    const float* inp_W      = (const float*)d_in[3];
    const float* conv_w     = (const float*)d_in[4];
    const float* conv_b     = (const float*)d_in[5];
    const float* xproj_W    = (const float*)d_in[6];
    const float* dt_W       = (const float*)d_in[7];
    const float* dt_b       = (const float*)d_in[8];
    const float* A_log      = (const float*)d_in[9];
    const float* Dv         = (const float*)d_in[10];
    const float* out_norm_w = (const float*)d_in[11];
    const float* out_W      = (const float*)d_in[12];
    float* out = (float*)d_out;

    float* ws  = (float*)d_ws;
    float* xz  = ws;                         // NROWS*2*DI (x_path half reused for scan out)
    float* xc  = xz + (long)NROWS * 2 * DI;  // NROWS*DI (conv out; later yn). xn aliases here.
    float* xn  = xc;                         // NROWS*DM (dead before xc is written)
    float* dbc = xc + (long)NROWS * DI;      // NROWS*33
    float* scal = dbc + (long)NROWS * 33;    // [0]=sum|inp_W|, [1]=sum|out_W|
    float* part = scal + 2;                  // 2*1024 partials

    rmsnorm2_kernel<<<NROWS, 256, 0, stream>>>(x, norm_w, inp_norm_w, xn);
    abssum_partial_kernel<<<1024, 256, 0, stream>>>(inp_W, 2 * DI * DM, part);
    reduce_partials_kernel<<<1, 512, 0, stream>>>(part, scal);
    abssum_partial_kernel<<<1024, 256, 0, stream>>>(out_W, DM * DI, part + 1024);
    reduce_partials_kernel<<<1, 512, 0, stream>>>(part + 1024, scal + 1);

    matmul_big_kernel<<<dim3(2 * DI / 128, NROWS / 128), 256, 0, stream>>>(
        xn, inp_W, nullptr, xz, NROWS, 2 * DI, DM, scal, 1.f / (2 * DI * DM));
    conv_silu_kernel<<<(NROWS * DI + 255) / 256, 256, 0, stream>>>(xz, conv_w, conv_b, xc);
    xproj_kernel<<<NROWS, 64, 0, stream>>>(xc, xproj_W, dbc);
    scan_kernel<<<B_SZ * (DI / 16), 256, 0, stream>>>(dbc, xc, xz, xz, A_log, dt_W, dt_b, Dv);
    rmsnorm_y_kernel<<<NROWS, 256, 0, stream>>>(xz, out_norm_w, xc);
    matmul_big_kernel<<<dim3(DM / 128, NROWS / 128), 256, 0, stream>>>(
        xc, out_W, x, out, NROWS, DM, DI, scal + 1, 1.f / (DM * DI));
}

// Round 5
// 806.516 us; speedup vs baseline: 5.1776x; 2.3209x over previous
//
#include <hip/hip_runtime.h>

#define B_SZ 2
#define L_SEQ 2048
#define DM 768
#define DI 1536
#define DS 16
#define NROWS (B_SZ * L_SEQ)   // 4096
#define NC 32                  // scan chunks per sequence
#define LC 64                  // L_SEQ / NC
#define CGD 6                  // DI / 256

__device__ __forceinline__ float softplusf(float x) {
    return (x > 20.f) ? x : log1pf(expf(x));
}

__device__ __forceinline__ float quantw(float w, float s, float inv_s) {
    float t = fminf(fmaxf(w * inv_s, -1.f), 1.f);
    return rintf(t) * s;
}

// ---- block reduction (blockDim.x multiple of 64, <=512) ----
__device__ float blockReduceSum(float v, float* sh) {
    int tid = threadIdx.x;
    int lane = tid & 63, w = tid >> 6;
#pragma unroll
    for (int off = 32; off; off >>= 1) v += __shfl_xor(v, off);
    if (lane == 0) sh[w] = v;
    __syncthreads();
    int nw = blockDim.x >> 6;
    float t = (tid < nw) ? sh[tid] : 0.f;
    if (w == 0) {
#pragma unroll
        for (int off = 4; off; off >>= 1) t += __shfl_xor(t, off);
    }
    if (tid == 0) sh[0] = t;
    __syncthreads();
    float r = sh[0];
    __syncthreads();
    return r;
}

// ---- fused rmsnorm(x,norm_w) then rmsnorm(.,inp_norm_w) -> xn fp32 ----
__global__ void rmsnorm2_kernel(const float* __restrict__ x, const float* __restrict__ w1,
                                const float* __restrict__ w2, float* __restrict__ xn) {
    __shared__ float sh[8];
    int row = blockIdx.x;
    const float* xr = x + (long)row * DM;
    float v[3];
    float ss = 0.f;
#pragma unroll
    for (int i = 0; i < 3; i++) {
        v[i] = xr[threadIdx.x + 256 * i];
        ss += v[i] * v[i];
    }
    ss = blockReduceSum(ss, sh);
    float r1 = rsqrtf(ss / DM + 1e-6f);
    float h[3];
    float ss2 = 0.f;
#pragma unroll
    for (int i = 0; i < 3; i++) {
        h[i] = v[i] * r1 * w1[threadIdx.x + 256 * i];
        ss2 += h[i] * h[i];
    }
    ss2 = blockReduceSum(ss2, sh);
    float r2 = rsqrtf(ss2 / DM + 1e-6f);
#pragma unroll
    for (int i = 0; i < 3; i++)
        xn[(long)row * DM + threadIdx.x + 256 * i] = h[i] * r2 * w2[threadIdx.x + 256 * i];
}

// ---- |W| partial sums, one value per block ----
__global__ void abssum_partial_kernel(const float* __restrict__ w, int n,
                                      float* __restrict__ partials) {
    __shared__ float sh[8];
    float s = 0.f;
    for (int i = blockIdx.x * blockDim.x + threadIdx.x; i < n; i += gridDim.x * blockDim.x)
        s += fabsf(w[i]);
    s = blockReduceSum(s, sh);
    if (threadIdx.x == 0) partials[blockIdx.x] = s;
}

// ---- reduce 1024 partials in fixed order ----
__global__ void reduce_partials_kernel(const float* __restrict__ partials,
                                       float* __restrict__ out) {
    __shared__ float sh[8];
    float s = partials[threadIdx.x] + partials[threadIdx.x + 512];
    s = blockReduceSum(s, sh);
    if (threadIdx.x == 0) out[0] = s;
}

// ---- C[M,N] = A[M,K] @ quant(B[N,K])^T (+resid), 128x128 tile, 8x8/thread ----
__global__ __launch_bounds__(256)
void matmul_big_kernel(const float* __restrict__ A, const float* __restrict__ Bm,
                       const float* __restrict__ resid, float* __restrict__ C,
                       int M, int N, int K,
                       const float* __restrict__ scal, float invn) {
    __shared__ float As[16][132], Bs[16][132];
    float s = fmaxf(scal[0] * invn, 1e-5f);
    float inv_s = 1.f / s;
    int tid = threadIdx.x;
    int tx = tid & 15, ty = tid >> 4;
    int m0 = blockIdx.y * 128, n0 = blockIdx.x * 128;
    int ar = tid >> 1;            // 0..127
    int akk = (tid & 1) * 8;      // 0 or 8
    const float* apb = A + (long)(m0 + ar) * K + akk;
    const float* bpb = Bm + (long)(n0 + ar) * K + akk;
    float acc[8][8] = {};
    for (int k0 = 0; k0 < K; k0 += 16) {
        float4 a0 = *(const float4*)(apb + k0);
        float4 a1 = *(const float4*)(apb + k0 + 4);
        float4 b0 = *(const float4*)(bpb + k0);
        float4 b1 = *(const float4*)(bpb + k0 + 4);
        As[akk + 0][ar] = a0.x; As[akk + 1][ar] = a0.y;
        As[akk + 2][ar] = a0.z; As[akk + 3][ar] = a0.w;
        As[akk + 4][ar] = a1.x; As[akk + 5][ar] = a1.y;
        As[akk + 6][ar] = a1.z; As[akk + 7][ar] = a1.w;
        Bs[akk + 0][ar] = quantw(b0.x, s, inv_s); Bs[akk + 1][ar] = quantw(b0.y, s, inv_s);
        Bs[akk + 2][ar] = quantw(b0.z, s, inv_s); Bs[akk + 3][ar] = quantw(b0.w, s, inv_s);
        Bs[akk + 4][ar] = quantw(b1.x, s, inv_s); Bs[akk + 5][ar] = quantw(b1.y, s, inv_s);
        Bs[akk + 6][ar] = quantw(b1.z, s, inv_s); Bs[akk + 7][ar] = quantw(b1.w, s, inv_s);
        __syncthreads();
#pragma unroll
        for (int k = 0; k < 16; k++) {
            float av[8], bv[8];
            *(float4*)(av)     = *(const float4*)&As[k][ty * 8];
            *(float4*)(av + 4) = *(const float4*)&As[k][ty * 8 + 4];
            *(float4*)(bv)     = *(const float4*)&Bs[k][tx * 4];
            *(float4*)(bv + 4) = *(const float4*)&Bs[k][64 + tx * 4];
#pragma unroll
            for (int i = 0; i < 8; i++)
#pragma unroll
                for (int j = 0; j < 8; j++)
                    acc[i][j] = fmaf(av[i], bv[j], acc[i][j]);
        }
        __syncthreads();
    }
#pragma unroll
    for (int i = 0; i < 8; i++) {
        long m = m0 + ty * 8 + i;
#pragma unroll
        for (int half = 0; half < 2; half++) {
            long idx = m * N + n0 + half * 64 + tx * 4;
            float4 v;
            v.x = acc[i][half * 4 + 0]; v.y = acc[i][half * 4 + 1];
            v.z = acc[i][half * 4 + 2]; v.w = acc[i][half * 4 + 3];
            if (resid) {
                float4 r4 = *(const float4*)(resid + idx);
                v.x += r4.x; v.y += r4.y; v.z += r4.z; v.w += r4.w;
            }
            *(float4*)(C + idx) = v;
        }
    }
}

// ---- causal depthwise conv (k=4) + bias + silu ----
__global__ void conv_silu_kernel(const float* __restrict__ xz, const float* __restrict__ cw,
                                 const float* __restrict__ cb, float* __restrict__ xc) {
    int id = blockIdx.x * blockDim.x + threadIdx.x;
    if (id >= NROWS * DI) return;
    int c = id % DI;
    int rl = id / DI;       // b*L + l
    int l = rl % L_SEQ;
    float acc = cb[c];
#pragma unroll
    for (int k = 0; k < 4; k++) {
        int ls = l - 3 + k;
        if (ls >= 0) acc = fmaf(xz[(long)(rl - 3 + k) * (2 * DI) + c], cw[c * 4 + k], acc);
    }
    xc[id] = acc / (1.f + expf(-acc));   // silu
}

// ---- dbc[row, 0..32] = xc[row,:] @ xproj_W^T ; one wave per row ----
__global__ void xproj_kernel(const float* __restrict__ xc, const float* __restrict__ xw,
                             float* __restrict__ dbc) {
    int row = blockIdx.x;
    int lane = threadIdx.x;  // 64
    float xr[24];
    const float* xrow = xc + (long)row * DI;
#pragma unroll
    for (int j = 0; j < 24; j++) xr[j] = xrow[lane + 64 * j];
    for (int o = 0; o < 33; o++) {
        const float* wr = xw + o * DI;
        float a = 0.f;
#pragma unroll
        for (int j = 0; j < 24; j++) a = fmaf(xr[j], wr[lane + 64 * j], a);
#pragma unroll
        for (int off = 32; off; off >>= 1) a += __shfl_xor(a, off);
        if (lane == 0) dbc[(long)row * 33 + o] = a;
    }
}

// ---- scan pass 1: per-chunk partial state (h from 0) + decay P = exp(A*sum dt) ----
// thread = one channel; block = 256 channels of chunk q, batch b
__global__ __launch_bounds__(256)
void scan_part_kernel(const float* __restrict__ dbc, const float* __restrict__ xc,
                      const float* __restrict__ A_log, const float* __restrict__ dt_W,
                      const float* __restrict__ dt_b,
                      float* __restrict__ P, float* __restrict__ hp) {
    __shared__ float sdt[LC];
    __shared__ float sB[LC][16];
    int tid = threadIdx.x;
    int cg = blockIdx.x % CGD;
    int bq = blockIdx.x / CGD;       // b*NC + q
    int b = bq / NC, q = bq % NC;
    int c = cg * 256 + tid;
    long row0 = (long)b * L_SEQ + q * LC;

    for (int idx = tid; idx < LC * 17; idx += 256) {
        int r = idx / 17, j = idx - r * 17;
        float v = dbc[(row0 + r) * 33 + j];
        if (j == 0) sdt[r] = v; else sB[r][j - 1] = v;
    }

    float dtw = dt_W[c], dtb = dt_b[c];
    float An[16];
    {
        const float4* ap = (const float4*)(A_log + c * 16);
#pragma unroll
        for (int k = 0; k < 4; k++) {
            float4 a = ap[k];
            An[4 * k + 0] = -expf(a.x); An[4 * k + 1] = -expf(a.y);
            An[4 * k + 2] = -expf(a.z); An[4 * k + 3] = -expf(a.w);
        }
    }
    float h[16];
#pragma unroll
    for (int n = 0; n < 16; n++) h[n] = 0.f;
    float S = 0.f;
    __syncthreads();

    for (int rr = 0; rr < LC; rr += 8) {
        float xv[8];
#pragma unroll
        for (int u = 0; u < 8; u++) xv[u] = xc[(row0 + rr + u) * DI + c];
#pragma unroll
        for (int u = 0; u < 8; u++) {
            int r = rr + u;
            float dt = softplusf(fmaf(sdt[r], dtw, dtb));
            S += dt;
            float bb[16];
            *(float4*)(bb + 0)  = *(const float4*)&sB[r][0];
            *(float4*)(bb + 4)  = *(const float4*)&sB[r][4];
            *(float4*)(bb + 8)  = *(const float4*)&sB[r][8];
            *(float4*)(bb + 12) = *(const float4*)&sB[r][12];
            float g = dt * xv[u];
#pragma unroll
            for (int n = 0; n < 16; n++) {
                float a = expf(dt * An[n]);
                h[n] = fmaf(a, h[n], g * bb[n]);
            }
        }
    }
    long o = ((long)bq * DI + c) * 16;
#pragma unroll
    for (int k = 0; k < 4; k++) {
        float4 pv, hv;
        pv.x = expf(An[4 * k + 0] * S); pv.y = expf(An[4 * k + 1] * S);
        pv.z = expf(An[4 * k + 2] * S); pv.w = expf(An[4 * k + 3] * S);
        hv.x = h[4 * k + 0]; hv.y = h[4 * k + 1];
        hv.z = h[4 * k + 2]; hv.w = h[4 * k + 3];
        *(float4*)(P + o + 4 * k)  = pv;
        *(float4*)(hp + o + 4 * k) = hv;
    }
}

// ---- scan pass 2: serial combine over chunks; hp[q] becomes h_in for chunk q ----
__global__ void scan_combine_kernel(const float* __restrict__ P, float* __restrict__ hp) {
    long g = (long)blockIdx.x * 256 + threadIdx.x;   // over B*DI*16
    int b = (int)(g / ((long)DI * 16));
    long rem = g - (long)b * DI * 16;
    float h = 0.f;
    for (int q = 0; q < NC; q++) {
        long o = ((long)(b * NC + q)) * (DI * 16) + rem;
        float Pv = P[o], hv = hp[o];
        hp[o] = h;                  // h_in for chunk q
        h = fmaf(Pv, h, hv);
    }
}

// ---- scan pass 3: re-run chunk from true h_in, emit y = C.h + x*D, gated by silu(z) ----
__global__ __launch_bounds__(256)
void scan_emit_kernel(const float* __restrict__ dbc, const float* __restrict__ xc,
                      float* __restrict__ xz,
                      const float* __restrict__ A_log, const float* __restrict__ dt_W,
                      const float* __restrict__ dt_b, const float* __restrict__ Dv,
                      const float* __restrict__ hin) {
    __shared__ float sdt[LC];
    __shared__ float sB[LC][16];
    __shared__ float sC[LC][16];
    int tid = threadIdx.x;
    int cg = blockIdx.x % CGD;
    int bq = blockIdx.x / CGD;
    int b = bq / NC, q = bq % NC;
    int c = cg * 256 + tid;
    long row0 = (long)b * L_SEQ + q * LC;

    for (int idx = tid; idx < LC * 33; idx += 256) {
        int r = idx / 33, j = idx - r * 33;
        float v = dbc[row0 * 33 + idx];        // fully contiguous
        if (j == 0)      sdt[r] = v;
        else if (j < 17) sB[r][j - 1] = v;
        else             sC[r][j - 17] = v;
    }

    float dtw = dt_W[c], dtb = dt_b[c], Dc = Dv[c];
    float An[16];
    {
        const float4* ap = (const float4*)(A_log + c * 16);
#pragma unroll
        for (int k = 0; k < 4; k++) {
            float4 a = ap[k];
            An[4 * k + 0] = -expf(a.x); An[4 * k + 1] = -expf(a.y);
            An[4 * k + 2] = -expf(a.z); An[4 * k + 3] = -expf(a.w);
        }
    }
    float h[16];
    {
        long o = ((long)bq * DI + c) * 16;
#pragma unroll
        for (int k = 0; k < 4; k++) {
            float4 hv = *(const float4*)(hin + o + 4 * k);
            h[4 * k + 0] = hv.x; h[4 * k + 1] = hv.y;
            h[4 * k + 2] = hv.z; h[4 * k + 3] = hv.w;
        }
    }
    __syncthreads();

    for (int rr = 0; rr < LC; rr += 8) {
        float xv[8], zv[8];
#pragma unroll
        for (int u = 0; u < 8; u++) xv[u] = xc[(row0 + rr + u) * DI + c];
#pragma unroll
        for (int u = 0; u < 8; u++) zv[u] = xz[(row0 + rr + u) * 2 * DI + DI + c];
#pragma unroll
        for (int u = 0; u < 8; u++) {
            int r = rr + u;
            float dt = softplusf(fmaf(sdt[r], dtw, dtb));
            float bb[16], cc[16];
            *(float4*)(bb + 0)  = *(const float4*)&sB[r][0];
            *(float4*)(bb + 4)  = *(const float4*)&sB[r][4];
            *(float4*)(bb + 8)  = *(const float4*)&sB[r][8];
            *(float4*)(bb + 12) = *(const float4*)&sB[r][12];
            *(float4*)(cc + 0)  = *(const float4*)&sC[r][0];
            *(float4*)(cc + 4)  = *(const float4*)&sC[r][4];
            *(float4*)(cc + 8)  = *(const float4*)&sC[r][8];
            *(float4*)(cc + 12) = *(const float4*)&sC[r][12];
            float g = dt * xv[u];
            float y = 0.f;
#pragma unroll
            for (int n = 0; n < 16; n++) {
                float a = expf(dt * An[n]);
                h[n] = fmaf(a, h[n], g * bb[n]);
                y = fmaf(h[n], cc[n], y);
            }
            float zz = zv[u];
            y = (y + xv[u] * Dc) * (zz / (1.f + expf(-zz)));
            xz[(row0 + r) * 2 * DI + c] = y;
        }
    }
}

// ---- rmsnorm over y (stride-2*DI rows) -> yn fp32 ----
__global__ void rmsnorm_y_kernel(const float* __restrict__ xz, const float* __restrict__ w,
                                 float* __restrict__ yn) {
    __shared__ float sh[8];
    int row = blockIdx.x;
    const float* yr = xz + (long)row * 2 * DI;
    float v[6];
    float ss = 0.f;
#pragma unroll
    for (int i = 0; i < 6; i++) {
        v[i] = yr[threadIdx.x + 256 * i];
        ss += v[i] * v[i];
    }
    ss = blockReduceSum(ss, sh);
    float r = rsqrtf(ss / DI + 1e-6f);
#pragma unroll
    for (int i = 0; i < 6; i++)
        yn[(long)row * DI + threadIdx.x + 256 * i] = v[i] * r * w[threadIdx.x + 256 * i];
}

extern "C" void kernel_launch(void* const* d_in, const int* in_sizes, int n_in,
                              void* d_out, int out_size, void* d_ws, size_t ws_size,
                              hipStream_t stream) {
    const float* x          = (const float*)d_in[0];
    const float* norm_w     = (const float*)d_in[1];
    const float* inp_norm_w = (const float*)d_in[2];
    const float* inp_W      = (const float*)d_in[3];
    const float* conv_w     = (const float*)d_in[4];
    const float* conv_b     = (const float*)d_in[5];
    const float* xproj_W    = (const float*)d_in[6];
    const float* dt_W       = (const float*)d_in[7];
    const float* dt_b       = (const float*)d_in[8];
    const float* A_log      = (const float*)d_in[9];
    const float* Dv         = (const float*)d_in[10];
    const float* out_norm_w = (const float*)d_in[11];
    const float* out_W      = (const float*)d_in[12];
    float* out = (float*)d_out;

    float* ws  = (float*)d_ws;
    float* xz  = ws;                         // NROWS*2*DI (x half reused for scan y out)
    float* xc  = xz + (long)NROWS * 2 * DI;  // NROWS*DI (conv out; later yn). xn aliases here.
    float* xn  = xc;                         // NROWS*DM (dead before xc is written)
    float* dbc = xc + (long)NROWS * DI;      // NROWS*33
    float* scal = dbc + (long)NROWS * 33;    // [0]=sum|inp_W|, [1]=sum|out_W|
    float* part = scal + 2;                  // 2*1024 partials
    float* Pbuf = part + 2048;               // B*NC*DI*16
    float* hp   = Pbuf + (long)B_SZ * NC * DI * 16;  // B*NC*DI*16

    rmsnorm2_kernel<<<NROWS, 256, 0, stream>>>(x, norm_w, inp_norm_w, xn);
    abssum_partial_kernel<<<1024, 256, 0, stream>>>(inp_W, 2 * DI * DM, part);
    reduce_partials_kernel<<<1, 512, 0, stream>>>(part, scal);
    abssum_partial_kernel<<<1024, 256, 0, stream>>>(out_W, DM * DI, part + 1024);
    reduce_partials_kernel<<<1, 512, 0, stream>>>(part + 1024, scal + 1);

    matmul_big_kernel<<<dim3(2 * DI / 128, NROWS / 128), 256, 0, stream>>>(
        xn, inp_W, nullptr, xz, NROWS, 2 * DI, DM, scal, 1.f / (2 * DI * DM));
    conv_silu_kernel<<<(NROWS * DI + 255) / 256, 256, 0, stream>>>(xz, conv_w, conv_b, xc);
    xproj_kernel<<<NROWS, 64, 0, stream>>>(xc, xproj_W, dbc);

    scan_part_kernel<<<B_SZ * NC * CGD, 256, 0, stream>>>(dbc, xc, A_log, dt_W, dt_b, Pbuf, hp);
    scan_combine_kernel<<<(B_SZ * DI * 16) / 256, 256, 0, stream>>>(Pbuf, hp);
    scan_emit_kernel<<<B_SZ * NC * CGD, 256, 0, stream>>>(dbc, xc, xz, A_log, dt_W, dt_b, Dv, hp);

    rmsnorm_y_kernel<<<NROWS, 256, 0, stream>>>(xz, out_norm_w, xc);
    matmul_big_kernel<<<dim3(DM / 128, NROWS / 128), 256, 0, stream>>>(
        xc, out_W, x, out, NROWS, DM, DI, scal + 1, 1.f / (DM * DI));
}

// Round 6
// 466.239 us; speedup vs baseline: 8.9564x; 1.7298x over previous
//
#include <hip/hip_runtime.h>
#include <hip/hip_bf16.h>

#define B_SZ 2
#define L_SEQ 2048
#define DM 768
#define DI 1536
#define DS 16
#define NROWS (B_SZ * L_SEQ)   // 4096
#define NC 32                  // scan chunks per sequence
#define LC 64                  // L_SEQ / NC
#define CGD 6                  // DI / 256
#define BK 32                  // gemm k-chunk

typedef short short8 __attribute__((ext_vector_type(8)));
typedef float float4v __attribute__((ext_vector_type(4)));

__device__ __forceinline__ float softplusf(float x) {
    return (x > 20.f) ? x : log1pf(expf(x));
}

__device__ __forceinline__ short f2bf(float f) {
    __hip_bfloat16 h = __float2bfloat16(f);
    return *reinterpret_cast<short*>(&h);
}

// ---- block reduction (blockDim.x multiple of 64, <=512) ----
__device__ float blockReduceSum(float v, float* sh) {
    int tid = threadIdx.x;
    int lane = tid & 63, w = tid >> 6;
#pragma unroll
    for (int off = 32; off; off >>= 1) v += __shfl_xor(v, off);
    if (lane == 0) sh[w] = v;
    __syncthreads();
    int nw = blockDim.x >> 6;
    float t = (tid < nw) ? sh[tid] : 0.f;
    if (w == 0) {
#pragma unroll
        for (int off = 4; off; off >>= 1) t += __shfl_xor(t, off);
    }
    if (tid == 0) sh[0] = t;
    __syncthreads();
    float r = sh[0];
    __syncthreads();
    return r;
}

// ---- fused double rmsnorm -> bf16 activations ----
__global__ void rmsnorm2_kernel(const float* __restrict__ x, const float* __restrict__ w1,
                                const float* __restrict__ w2, short* __restrict__ xn) {
    __shared__ float sh[8];
    int row = blockIdx.x;
    const float* xr = x + (long)row * DM;
    float v[3];
    float ss = 0.f;
#pragma unroll
    for (int i = 0; i < 3; i++) {
        v[i] = xr[threadIdx.x + 256 * i];
        ss += v[i] * v[i];
    }
    ss = blockReduceSum(ss, sh);
    float r1 = rsqrtf(ss / DM + 1e-6f);
    float h[3];
    float ss2 = 0.f;
#pragma unroll
    for (int i = 0; i < 3; i++) {
        h[i] = v[i] * r1 * w1[threadIdx.x + 256 * i];
        ss2 += h[i] * h[i];
    }
    ss2 = blockReduceSum(ss2, sh);
    float r2 = rsqrtf(ss2 / DM + 1e-6f);
#pragma unroll
    for (int i = 0; i < 3; i++)
        xn[(long)row * DM + threadIdx.x + 256 * i] = f2bf(h[i] * r2 * w2[threadIdx.x + 256 * i]);
}

// ---- |W| partial sums ----
__global__ void abssum_partial_kernel(const float* __restrict__ w, int n,
                                      float* __restrict__ partials) {
    __shared__ float sh[8];
    float s = 0.f;
    for (int i = blockIdx.x * blockDim.x + threadIdx.x; i < n; i += gridDim.x * blockDim.x)
        s += fabsf(w[i]);
    s = blockReduceSum(s, sh);
    if (threadIdx.x == 0) partials[blockIdx.x] = s;
}

__global__ void reduce_partials_kernel(const float* __restrict__ partials,
                                       float* __restrict__ out) {
    __shared__ float sh[8];
    float s = partials[threadIdx.x] + partials[threadIdx.x + 512];
    s = blockReduceSum(s, sh);
    if (threadIdx.x == 0) out[0] = s;
}

// ---- ternary quantize -> bf16 {-1,0,+1} (exact) ----
__global__ void quant_bf16_kernel(const float* __restrict__ w, int n,
                                  const float* __restrict__ scal, float invn,
                                  short* __restrict__ wq) {
    int i = blockIdx.x * blockDim.x + threadIdx.x;
    if (i >= n) return;
    float s = fmaxf(scal[0] * invn, 1e-5f);
    float t = rintf(fminf(fmaxf(w[i] / s, -1.f), 1.f));
    wq[i] = (t == 0.f) ? (short)0 : (t > 0.f ? (short)0x3F80 : (short)0xBF80);
}

// ---- C[M,N] = (A[M,K]bf16 @ Bq[N,K]bf16^T)*s (+resid), MFMA 16x16x32 ----
// block 256 = 4 waves (2x2); wave computes 64x64 (4x4 mfma tiles); BK=32
__global__ __launch_bounds__(256)
void gemm_mfma_kernel(const short* __restrict__ A, const short* __restrict__ Bq,
                      const float* __restrict__ resid, float* __restrict__ C,
                      int M, int N, int K,
                      const float* __restrict__ scal, float invn) {
    __shared__ __align__(16) short As[128 * BK];
    __shared__ __align__(16) short Bs[128 * BK];
    int tid = threadIdx.x;
    int lane = tid & 63, wave = tid >> 6;
    int wx = wave & 1, wy = wave >> 1;
    int ln = lane & 15, qd = lane >> 4;
    int m0 = blockIdx.y * 128, n0 = blockIdx.x * 128;

    // staging: thread t -> row srow=t>>1, 16B chunks {j0, j0+2}; XOR-swizzled LDS
    int srow = tid >> 1;
    int j0 = tid & 1;
    int s_r = (srow >> 1) & 3;
    const short* gA = A + (long)(m0 + srow) * K + j0 * 8;
    const short* gB = Bq + (long)(n0 + srow) * K + j0 * 8;
    short* wA0 = &As[srow * BK + ((j0 ^ s_r)) * 8];
    short* wA1 = &As[srow * BK + (((j0 + 2) ^ s_r)) * 8];
    short* wB0 = &Bs[srow * BK + ((j0 ^ s_r)) * 8];
    short* wB1 = &Bs[srow * BK + (((j0 + 2) ^ s_r)) * 8];

    // fragment read offsets (constant over k-loop)
    int aoff[4], boff[4];
#pragma unroll
    for (int i = 0; i < 4; i++) {
        int ra = wy * 64 + i * 16 + ln;
        aoff[i] = ra * BK + ((qd ^ ((ra >> 1) & 3)) * 8);
        int rb = wx * 64 + i * 16 + ln;
        boff[i] = rb * BK + ((qd ^ ((rb >> 1) & 3)) * 8);
    }

    float4v acc[4][4] = {};
    short8 pa0 = *(const short8*)(gA);
    short8 pa1 = *(const short8*)(gA + 16);
    short8 pb0 = *(const short8*)(gB);
    short8 pb1 = *(const short8*)(gB + 16);

    int nch = K >> 5;
    for (int kc = 0; kc < nch; kc++) {
        __syncthreads();
        *(short8*)wA0 = pa0; *(short8*)wA1 = pa1;
        *(short8*)wB0 = pb0; *(short8*)wB1 = pb1;
        __syncthreads();
        if (kc + 1 < nch) {
            int k0 = (kc + 1) << 5;
            pa0 = *(const short8*)(gA + k0);
            pa1 = *(const short8*)(gA + k0 + 16);
            pb0 = *(const short8*)(gB + k0);
            pb1 = *(const short8*)(gB + k0 + 16);
        }
        short8 av[4], bv[4];
#pragma unroll
        for (int i = 0; i < 4; i++) av[i] = *(const short8*)&As[aoff[i]];
#pragma unroll
        for (int j = 0; j < 4; j++) bv[j] = *(const short8*)&Bs[boff[j]];
#pragma unroll
        for (int i = 0; i < 4; i++)
#pragma unroll
            for (int j = 0; j < 4; j++)
                acc[i][j] = __builtin_amdgcn_mfma_f32_16x16x32_bf16(av[i], bv[j], acc[i][j], 0, 0, 0);
    }

    float s = fmaxf(scal[0] * invn, 1e-5f);
#pragma unroll
    for (int i = 0; i < 4; i++) {
        int mbase = m0 + wy * 64 + i * 16 + qd * 4;
#pragma unroll
        for (int j = 0; j < 4; j++) {
            int nn = n0 + wx * 64 + j * 16 + ln;
#pragma unroll
            for (int r = 0; r < 4; r++) {
                long idx = (long)(mbase + r) * N + nn;
                float v = acc[i][j][r] * s;
                if (resid) v += resid[idx];
                C[idx] = v;
            }
        }
    }
}

// ---- causal depthwise conv (k=4) + bias + silu ----
__global__ void conv_silu_kernel(const float* __restrict__ xz, const float* __restrict__ cw,
                                 const float* __restrict__ cb, float* __restrict__ xc) {
    int id = blockIdx.x * blockDim.x + threadIdx.x;
    if (id >= NROWS * DI) return;
    int c = id % DI;
    int rl = id / DI;
    int l = rl % L_SEQ;
    float acc = cb[c];
#pragma unroll
    for (int k = 0; k < 4; k++) {
        int ls = l - 3 + k;
        if (ls >= 0) acc = fmaf(xz[(long)(rl - 3 + k) * (2 * DI) + c], cw[c * 4 + k], acc);
    }
    xc[id] = acc / (1.f + expf(-acc));
}

// ---- dbc[row, 0..32] = xc[row,:] @ xproj_W^T ----
__global__ void xproj_kernel(const float* __restrict__ xc, const float* __restrict__ xw,
                             float* __restrict__ dbc) {
    int row = blockIdx.x;
    int lane = threadIdx.x;  // 64
    float xr[24];
    const float* xrow = xc + (long)row * DI;
#pragma unroll
    for (int j = 0; j < 24; j++) xr[j] = xrow[lane + 64 * j];
    for (int o = 0; o < 33; o++) {
        const float* wr = xw + o * DI;
        float a = 0.f;
#pragma unroll
        for (int j = 0; j < 24; j++) a = fmaf(xr[j], wr[lane + 64 * j], a);
#pragma unroll
        for (int off = 32; off; off >>= 1) a += __shfl_xor(a, off);
        if (lane == 0) dbc[(long)row * 33 + o] = a;
    }
}

// ---- scan pass 1: per-chunk partial state + decay ----
__global__ __launch_bounds__(256)
void scan_part_kernel(const float* __restrict__ dbc, const float* __restrict__ xc,
                      const float* __restrict__ A_log, const float* __restrict__ dt_W,
                      const float* __restrict__ dt_b,
                      float* __restrict__ P, float* __restrict__ hp) {
    __shared__ float sdt[LC];
    __shared__ float sB[LC][16];
    int tid = threadIdx.x;
    int cg = blockIdx.x % CGD;
    int bq = blockIdx.x / CGD;
    int b = bq / NC, q = bq % NC;
    int c = cg * 256 + tid;
    long row0 = (long)b * L_SEQ + q * LC;

    for (int idx = tid; idx < LC * 17; idx += 256) {
        int r = idx / 17, j = idx - r * 17;
        float v = dbc[(row0 + r) * 33 + j];
        if (j == 0) sdt[r] = v; else sB[r][j - 1] = v;
    }

    float dtw = dt_W[c], dtb = dt_b[c];
    float An[16];
    {
        const float4* ap = (const float4*)(A_log + c * 16);
#pragma unroll
        for (int k = 0; k < 4; k++) {
            float4 a = ap[k];
            An[4 * k + 0] = -expf(a.x); An[4 * k + 1] = -expf(a.y);
            An[4 * k + 2] = -expf(a.z); An[4 * k + 3] = -expf(a.w);
        }
    }
    float h[16];
#pragma unroll
    for (int n = 0; n < 16; n++) h[n] = 0.f;
    float S = 0.f;
    __syncthreads();

    for (int rr = 0; rr < LC; rr += 8) {
        float xv[8];
#pragma unroll
        for (int u = 0; u < 8; u++) xv[u] = xc[(row0 + rr + u) * DI + c];
#pragma unroll
        for (int u = 0; u < 8; u++) {
            int r = rr + u;
            float dt = softplusf(fmaf(sdt[r], dtw, dtb));
            S += dt;
            float bb[16];
            *(float4*)(bb + 0)  = *(const float4*)&sB[r][0];
            *(float4*)(bb + 4)  = *(const float4*)&sB[r][4];
            *(float4*)(bb + 8)  = *(const float4*)&sB[r][8];
            *(float4*)(bb + 12) = *(const float4*)&sB[r][12];
            float g = dt * xv[u];
#pragma unroll
            for (int n = 0; n < 16; n++) {
                float a = expf(dt * An[n]);
                h[n] = fmaf(a, h[n], g * bb[n]);
            }
        }
    }
    long o = ((long)bq * DI + c) * 16;
#pragma unroll
    for (int k = 0; k < 4; k++) {
        float4 pv, hv;
        pv.x = expf(An[4 * k + 0] * S); pv.y = expf(An[4 * k + 1] * S);
        pv.z = expf(An[4 * k + 2] * S); pv.w = expf(An[4 * k + 3] * S);
        hv.x = h[4 * k + 0]; hv.y = h[4 * k + 1];
        hv.z = h[4 * k + 2]; hv.w = h[4 * k + 3];
        *(float4*)(P + o + 4 * k)  = pv;
        *(float4*)(hp + o + 4 * k) = hv;
    }
}

// ---- scan pass 2: serial combine over chunks ----
__global__ void scan_combine_kernel(const float* __restrict__ P, float* __restrict__ hp) {
    long g = (long)blockIdx.x * 256 + threadIdx.x;
    int b = (int)(g / ((long)DI * 16));
    long rem = g - (long)b * DI * 16;
    float h = 0.f;
    for (int q = 0; q < NC; q++) {
        long o = ((long)(b * NC + q)) * (DI * 16) + rem;
        float Pv = P[o], hv = hp[o];
        hp[o] = h;
        h = fmaf(Pv, h, hv);
    }
}

// ---- scan pass 3: re-run chunk from h_in, emit gated y ----
__global__ __launch_bounds__(256)
void scan_emit_kernel(const float* __restrict__ dbc, const float* __restrict__ xc,
                      float* __restrict__ xz,
                      const float* __restrict__ A_log, const float* __restrict__ dt_W,
                      const float* __restrict__ dt_b, const float* __restrict__ Dv,
                      const float* __restrict__ hin) {
    __shared__ float sdt[LC];
    __shared__ float sB[LC][16];
    __shared__ float sC[LC][16];
    int tid = threadIdx.x;
    int cg = blockIdx.x % CGD;
    int bq = blockIdx.x / CGD;
    int b = bq / NC, q = bq % NC;
    int c = cg * 256 + tid;
    long row0 = (long)b * L_SEQ + q * LC;

    for (int idx = tid; idx < LC * 33; idx += 256) {
        int r = idx / 33, j = idx - r * 33;
        float v = dbc[row0 * 33 + idx];
        if (j == 0)      sdt[r] = v;
        else if (j < 17) sB[r][j - 1] = v;
        else             sC[r][j - 17] = v;
    }

    float dtw = dt_W[c], dtb = dt_b[c], Dc = Dv[c];
    float An[16];
    {
        const float4* ap = (const float4*)(A_log + c * 16);
#pragma unroll
        for (int k = 0; k < 4; k++) {
            float4 a = ap[k];
            An[4 * k + 0] = -expf(a.x); An[4 * k + 1] = -expf(a.y);
            An[4 * k + 2] = -expf(a.z); An[4 * k + 3] = -expf(a.w);
        }
    }
    float h[16];
    {
        long o = ((long)bq * DI + c) * 16;
#pragma unroll
        for (int k = 0; k < 4; k++) {
            float4 hv = *(const float4*)(hin + o + 4 * k);
            h[4 * k + 0] = hv.x; h[4 * k + 1] = hv.y;
            h[4 * k + 2] = hv.z; h[4 * k + 3] = hv.w;
        }
    }
    __syncthreads();

    for (int rr = 0; rr < LC; rr += 8) {
        float xv[8], zv[8];
#pragma unroll
        for (int u = 0; u < 8; u++) xv[u] = xc[(row0 + rr + u) * DI + c];
#pragma unroll
        for (int u = 0; u < 8; u++) zv[u] = xz[(row0 + rr + u) * 2 * DI + DI + c];
#pragma unroll
        for (int u = 0; u < 8; u++) {
            int r = rr + u;
            float dt = softplusf(fmaf(sdt[r], dtw, dtb));
            float bb[16], cc[16];
            *(float4*)(bb + 0)  = *(const float4*)&sB[r][0];
            *(float4*)(bb + 4)  = *(const float4*)&sB[r][4];
            *(float4*)(bb + 8)  = *(const float4*)&sB[r][8];
            *(float4*)(bb + 12) = *(const float4*)&sB[r][12];
            *(float4*)(cc + 0)  = *(const float4*)&sC[r][0];
            *(float4*)(cc + 4)  = *(const float4*)&sC[r][4];
            *(float4*)(cc + 8)  = *(const float4*)&sC[r][8];
            *(float4*)(cc + 12) = *(const float4*)&sC[r][12];
            float g = dt * xv[u];
            float y = 0.f;
#pragma unroll
            for (int n = 0; n < 16; n++) {
                float a = expf(dt * An[n]);
                h[n] = fmaf(a, h[n], g * bb[n]);
                y = fmaf(h[n], cc[n], y);
            }
            float zz = zv[u];
            y = (y + xv[u] * Dc) * (zz / (1.f + expf(-zz)));
            xz[(row0 + r) * 2 * DI + c] = y;
        }
    }
}

// ---- rmsnorm over y (stride-2*DI rows) -> bf16 yn ----
__global__ void rmsnorm_y_kernel(const float* __restrict__ xz, const float* __restrict__ w,
                                 short* __restrict__ yn) {
    __shared__ float sh[8];
    int row = blockIdx.x;
    const float* yr = xz + (long)row * 2 * DI;
    float v[6];
    float ss = 0.f;
#pragma unroll
    for (int i = 0; i < 6; i++) {
        v[i] = yr[threadIdx.x + 256 * i];
        ss += v[i] * v[i];
    }
    ss = blockReduceSum(ss, sh);
    float r = rsqrtf(ss / DI + 1e-6f);
#pragma unroll
    for (int i = 0; i < 6; i++)
        yn[(long)row * DI + threadIdx.x + 256 * i] = f2bf(v[i] * r * w[threadIdx.x + 256 * i]);
}

extern "C" void kernel_launch(void* const* d_in, const int* in_sizes, int n_in,
                              void* d_out, int out_size, void* d_ws, size_t ws_size,
                              hipStream_t stream) {
    const float* x          = (const float*)d_in[0];
    const float* norm_w     = (const float*)d_in[1];
    const float* inp_norm_w = (const float*)d_in[2];
    const float* inp_W      = (const float*)d_in[3];
    const float* conv_w     = (const float*)d_in[4];
    const float* conv_b     = (const float*)d_in[5];
    const float* xproj_W    = (const float*)d_in[6];
    const float* dt_W       = (const float*)d_in[7];
    const float* dt_b       = (const float*)d_in[8];
    const float* A_log      = (const float*)d_in[9];
    const float* Dv         = (const float*)d_in[10];
    const float* out_norm_w = (const float*)d_in[11];
    const float* out_W      = (const float*)d_in[12];
    float* out = (float*)d_out;

    float* ws  = (float*)d_ws;
    float* xz  = ws;                         // NROWS*2*DI fp32
    float* xc  = xz + (long)NROWS * 2 * DI;  // NROWS*DI fp32 (conv out)
    float* dbc = xc + (long)NROWS * DI;      // NROWS*33
    float* scal = dbc + (long)NROWS * 33;    // 2
    float* part = scal + 2;                  // 2048
    float* Pbuf = part + 2048;               // B*NC*DI*16 fp32  (Wq1 overlaid pre-scan)
    float* hp   = Pbuf + (long)B_SZ * NC * DI * 16;
    short* Wq2  = (short*)(hp + (long)B_SZ * NC * DI * 16);  // DM*DI bf16

    short* A1  = (short*)xc;     // NROWS*DM bf16, dead before conv writes xc
    short* Wq1 = (short*)Pbuf;   // 2*DI*DM bf16, dead before scan_part writes Pbuf
    short* Yn  = (short*)xc;     // NROWS*DI bf16, written after xc is consumed

    rmsnorm2_kernel<<<NROWS, 256, 0, stream>>>(x, norm_w, inp_norm_w, A1);
    abssum_partial_kernel<<<1024, 256, 0, stream>>>(inp_W, 2 * DI * DM, part);
    reduce_partials_kernel<<<1, 512, 0, stream>>>(part, scal);
    abssum_partial_kernel<<<1024, 256, 0, stream>>>(out_W, DM * DI, part + 1024);
    reduce_partials_kernel<<<1, 512, 0, stream>>>(part + 1024, scal + 1);
    quant_bf16_kernel<<<(2 * DI * DM + 255) / 256, 256, 0, stream>>>(
        inp_W, 2 * DI * DM, scal, 1.f / (2 * DI * DM), Wq1);
    quant_bf16_kernel<<<(DM * DI + 255) / 256, 256, 0, stream>>>(
        out_W, DM * DI, scal + 1, 1.f / (DM * DI), Wq2);

    gemm_mfma_kernel<<<dim3(2 * DI / 128, NROWS / 128), 256, 0, stream>>>(
        A1, Wq1, nullptr, xz, NROWS, 2 * DI, DM, scal, 1.f / (2 * DI * DM));
    conv_silu_kernel<<<(NROWS * DI + 255) / 256, 256, 0, stream>>>(xz, conv_w, conv_b, xc);
    xproj_kernel<<<NROWS, 64, 0, stream>>>(xc, xproj_W, dbc);

    scan_part_kernel<<<B_SZ * NC * CGD, 256, 0, stream>>>(dbc, xc, A_log, dt_W, dt_b, Pbuf, hp);
    scan_combine_kernel<<<(B_SZ * DI * 16) / 256, 256, 0, stream>>>(Pbuf, hp);
    scan_emit_kernel<<<B_SZ * NC * CGD, 256, 0, stream>>>(dbc, xc, xz, A_log, dt_W, dt_b, Dv, hp);

    rmsnorm_y_kernel<<<NROWS, 256, 0, stream>>>(xz, out_norm_w, Yn);
    gemm_mfma_kernel<<<dim3(DM / 128, NROWS / 128), 256, 0, stream>>>(
        Yn, Wq2, x, out, NROWS, DM, DI, scal + 1, 1.f / (DM * DI));
}

// Round 7
// 361.982 us; speedup vs baseline: 11.5360x; 1.2880x over previous
//
#include <hip/hip_runtime.h>
#include <hip/hip_bf16.h>

#define B_SZ 2
#define L_SEQ 2048
#define DM 768
#define DI 1536
#define DS 16
#define NROWS (B_SZ * L_SEQ)   // 4096
#define NC 64                  // scan chunks per sequence
#define LC 32                  // L_SEQ / NC
#define CGD 6                  // DI / 256
#define BK 32                  // gemm k-chunk
#define LOG2E 1.44269504088896340736f

typedef short short8 __attribute__((ext_vector_type(8)));
typedef float float4v __attribute__((ext_vector_type(4)));

// fast softplus: abs error ~1e-7, fine for dt
__device__ __forceinline__ float softplus_fast(float x) {
    return (x > 20.f) ? x : __logf(1.f + __expf(x));
}

__device__ __forceinline__ float silu_fast(float z) {
    return z / (1.f + __expf(-z));
}

__device__ __forceinline__ short f2bf(float f) {
    __hip_bfloat16 h = __float2bfloat16(f);
    return *reinterpret_cast<short*>(&h);
}

// ---- block reduction (blockDim.x multiple of 64, <=512) ----
__device__ float blockReduceSum(float v, float* sh) {
    int tid = threadIdx.x;
    int lane = tid & 63, w = tid >> 6;
#pragma unroll
    for (int off = 32; off; off >>= 1) v += __shfl_xor(v, off);
    if (lane == 0) sh[w] = v;
    __syncthreads();
    int nw = blockDim.x >> 6;
    float t = (tid < nw) ? sh[tid] : 0.f;
    if (w == 0) {
#pragma unroll
        for (int off = 4; off; off >>= 1) t += __shfl_xor(t, off);
    }
    if (tid == 0) sh[0] = t;
    __syncthreads();
    float r = sh[0];
    __syncthreads();
    return r;
}

// ---- fused double rmsnorm -> bf16 activations ----
__global__ void rmsnorm2_kernel(const float* __restrict__ x, const float* __restrict__ w1,
                                const float* __restrict__ w2, short* __restrict__ xn) {
    __shared__ float sh[8];
    int row = blockIdx.x;
    const float* xr = x + (long)row * DM;
    float v[3];
    float ss = 0.f;
#pragma unroll
    for (int i = 0; i < 3; i++) {
        v[i] = xr[threadIdx.x + 256 * i];
        ss += v[i] * v[i];
    }
    ss = blockReduceSum(ss, sh);
    float r1 = rsqrtf(ss / DM + 1e-6f);
    float h[3];
    float ss2 = 0.f;
#pragma unroll
    for (int i = 0; i < 3; i++) {
        h[i] = v[i] * r1 * w1[threadIdx.x + 256 * i];
        ss2 += h[i] * h[i];
    }
    ss2 = blockReduceSum(ss2, sh);
    float r2 = rsqrtf(ss2 / DM + 1e-6f);
#pragma unroll
    for (int i = 0; i < 3; i++)
        xn[(long)row * DM + threadIdx.x + 256 * i] = f2bf(h[i] * r2 * w2[threadIdx.x + 256 * i]);
}

// ---- |W| partial sums ----
__global__ void abssum_partial_kernel(const float* __restrict__ w, int n,
                                      float* __restrict__ partials) {
    __shared__ float sh[8];
    float s = 0.f;
    for (int i = blockIdx.x * blockDim.x + threadIdx.x; i < n; i += gridDim.x * blockDim.x)
        s += fabsf(w[i]);
    s = blockReduceSum(s, sh);
    if (threadIdx.x == 0) partials[blockIdx.x] = s;
}

__global__ void reduce_partials_kernel(const float* __restrict__ partials,
                                       float* __restrict__ out) {
    __shared__ float sh[8];
    float s = partials[threadIdx.x] + partials[threadIdx.x + 512];
    s = blockReduceSum(s, sh);
    if (threadIdx.x == 0) out[0] = s;
}

// ---- ternary quantize -> bf16 {-1,0,+1} (exact) ----
__global__ void quant_bf16_kernel(const float* __restrict__ w, int n,
                                  const float* __restrict__ scal, float invn,
                                  short* __restrict__ wq) {
    int i = blockIdx.x * blockDim.x + threadIdx.x;
    if (i >= n) return;
    float s = fmaxf(scal[0] * invn, 1e-5f);
    float t = rintf(fminf(fmaxf(w[i] / s, -1.f), 1.f));
    wq[i] = (t == 0.f) ? (short)0 : (t > 0.f ? (short)0x3F80 : (short)0xBF80);
}

// ---- C[M,N] = (A[M,K]bf16 @ Bq[N,K]bf16^T)*s (+resid), MFMA 16x16x32 ----
__global__ __launch_bounds__(256)
void gemm_mfma_kernel(const short* __restrict__ A, const short* __restrict__ Bq,
                      const float* __restrict__ resid, float* __restrict__ C,
                      int M, int N, int K,
                      const float* __restrict__ scal, float invn) {
    __shared__ __align__(16) short As[128 * BK];
    __shared__ __align__(16) short Bs[128 * BK];
    int tid = threadIdx.x;
    int lane = tid & 63, wave = tid >> 6;
    int wx = wave & 1, wy = wave >> 1;
    int ln = lane & 15, qd = lane >> 4;
    int m0 = blockIdx.y * 128, n0 = blockIdx.x * 128;

    int srow = tid >> 1;
    int j0 = tid & 1;
    int s_r = (srow >> 1) & 3;
    const short* gA = A + (long)(m0 + srow) * K + j0 * 8;
    const short* gB = Bq + (long)(n0 + srow) * K + j0 * 8;
    short* wA0 = &As[srow * BK + ((j0 ^ s_r)) * 8];
    short* wA1 = &As[srow * BK + (((j0 + 2) ^ s_r)) * 8];
    short* wB0 = &Bs[srow * BK + ((j0 ^ s_r)) * 8];
    short* wB1 = &Bs[srow * BK + (((j0 + 2) ^ s_r)) * 8];

    int aoff[4], boff[4];
#pragma unroll
    for (int i = 0; i < 4; i++) {
        int ra = wy * 64 + i * 16 + ln;
        aoff[i] = ra * BK + ((qd ^ ((ra >> 1) & 3)) * 8);
        int rb = wx * 64 + i * 16 + ln;
        boff[i] = rb * BK + ((qd ^ ((rb >> 1) & 3)) * 8);
    }

    float4v acc[4][4] = {};
    short8 pa0 = *(const short8*)(gA);
    short8 pa1 = *(const short8*)(gA + 16);
    short8 pb0 = *(const short8*)(gB);
    short8 pb1 = *(const short8*)(gB + 16);

    int nch = K >> 5;
    for (int kc = 0; kc < nch; kc++) {
        __syncthreads();
        *(short8*)wA0 = pa0; *(short8*)wA1 = pa1;
        *(short8*)wB0 = pb0; *(short8*)wB1 = pb1;
        __syncthreads();
        if (kc + 1 < nch) {
            int k0 = (kc + 1) << 5;
            pa0 = *(const short8*)(gA + k0);
            pa1 = *(const short8*)(gA + k0 + 16);
            pb0 = *(const short8*)(gB + k0);
            pb1 = *(const short8*)(gB + k0 + 16);
        }
        short8 av[4], bv[4];
#pragma unroll
        for (int i = 0; i < 4; i++) av[i] = *(const short8*)&As[aoff[i]];
#pragma unroll
        for (int j = 0; j < 4; j++) bv[j] = *(const short8*)&Bs[boff[j]];
#pragma unroll
        for (int i = 0; i < 4; i++)
#pragma unroll
            for (int j = 0; j < 4; j++)
                acc[i][j] = __builtin_amdgcn_mfma_f32_16x16x32_bf16(av[i], bv[j], acc[i][j], 0, 0, 0);
    }

    float s = fmaxf(scal[0] * invn, 1e-5f);
#pragma unroll
    for (int i = 0; i < 4; i++) {
        int mbase = m0 + wy * 64 + i * 16 + qd * 4;
#pragma unroll
        for (int j = 0; j < 4; j++) {
            int nn = n0 + wx * 64 + j * 16 + ln;
#pragma unroll
            for (int r = 0; r < 4; r++) {
                long idx = (long)(mbase + r) * N + nn;
                float v = acc[i][j][r] * s;
                if (resid) v += resid[idx];
                C[idx] = v;
            }
        }
    }
}

// ---- causal depthwise conv (k=4) + bias + silu ----
__global__ void conv_silu_kernel(const float* __restrict__ xz, const float* __restrict__ cw,
                                 const float* __restrict__ cb, float* __restrict__ xc) {
    int id = blockIdx.x * blockDim.x + threadIdx.x;
    if (id >= NROWS * DI) return;
    int c = id % DI;
    int rl = id / DI;
    int l = rl % L_SEQ;
    float acc = cb[c];
#pragma unroll
    for (int k = 0; k < 4; k++) {
        int ls = l - 3 + k;
        if (ls >= 0) acc = fmaf(xz[(long)(rl - 3 + k) * (2 * DI) + c], cw[c * 4 + k], acc);
    }
    xc[id] = acc * (1.f / (1.f + __expf(-acc)));
}

// ---- dbc[row, 0..32] = xc[row,:] @ xproj_W^T ----
__global__ void xproj_kernel(const float* __restrict__ xc, const float* __restrict__ xw,
                             float* __restrict__ dbc) {
    int row = blockIdx.x;
    int lane = threadIdx.x;  // 64
    float xr[24];
    const float* xrow = xc + (long)row * DI;
#pragma unroll
    for (int j = 0; j < 24; j++) xr[j] = xrow[lane + 64 * j];
    for (int o = 0; o < 33; o++) {
        const float* wr = xw + o * DI;
        float a = 0.f;
#pragma unroll
        for (int j = 0; j < 24; j++) a = fmaf(xr[j], wr[lane + 64 * j], a);
#pragma unroll
        for (int off = 32; off; off >>= 1) a += __shfl_xor(a, off);
        if (lane == 0) dbc[(long)row * 33 + o] = a;
    }
}

// ---- scan pass 1: per-chunk partial state + decay P = exp2(An2*sum dt) ----
__global__ __launch_bounds__(256)
void scan_part_kernel(const float* __restrict__ dbc, const float* __restrict__ xc,
                      const float* __restrict__ A_log, const float* __restrict__ dt_W,
                      const float* __restrict__ dt_b,
                      float* __restrict__ P, float* __restrict__ hp) {
    __shared__ float sdt[LC];
    __shared__ float sB[LC][16];
    int tid = threadIdx.x;
    int cg = blockIdx.x % CGD;
    int bq = blockIdx.x / CGD;
    int b = bq / NC, q = bq % NC;
    int c = cg * 256 + tid;
    long row0 = (long)b * L_SEQ + q * LC;

    for (int idx = tid; idx < LC * 17; idx += 256) {
        int r = idx / 17, j = idx - r * 17;
        float v = dbc[(row0 + r) * 33 + j];
        if (j == 0) sdt[r] = v; else sB[r][j - 1] = v;
    }

    float dtw = dt_W[c], dtb = dt_b[c];
    float An2[16];   // -exp(A_log) * log2(e)  (exp2-folded decay)
    {
        const float4* ap = (const float4*)(A_log + c * 16);
#pragma unroll
        for (int k = 0; k < 4; k++) {
            float4 a = ap[k];
            An2[4 * k + 0] = -__expf(a.x) * LOG2E; An2[4 * k + 1] = -__expf(a.y) * LOG2E;
            An2[4 * k + 2] = -__expf(a.z) * LOG2E; An2[4 * k + 3] = -__expf(a.w) * LOG2E;
        }
    }
    float h[16];
#pragma unroll
    for (int n = 0; n < 16; n++) h[n] = 0.f;
    float S = 0.f;
    __syncthreads();

    for (int rr = 0; rr < LC; rr += 8) {
        float xv[8];
#pragma unroll
        for (int u = 0; u < 8; u++) xv[u] = xc[(row0 + rr + u) * DI + c];
#pragma unroll
        for (int u = 0; u < 8; u++) {
            int r = rr + u;
            float dt = softplus_fast(fmaf(sdt[r], dtw, dtb));
            S += dt;
            float bb[16];
            *(float4*)(bb + 0)  = *(const float4*)&sB[r][0];
            *(float4*)(bb + 4)  = *(const float4*)&sB[r][4];
            *(float4*)(bb + 8)  = *(const float4*)&sB[r][8];
            *(float4*)(bb + 12) = *(const float4*)&sB[r][12];
            float g = dt * xv[u];
#pragma unroll
            for (int n = 0; n < 16; n++) {
                float a = exp2f(dt * An2[n]);
                h[n] = fmaf(a, h[n], g * bb[n]);
            }
        }
    }
    long o = ((long)bq * DI + c) * 16;
#pragma unroll
    for (int k = 0; k < 4; k++) {
        float4 pv, hv;
        pv.x = exp2f(An2[4 * k + 0] * S); pv.y = exp2f(An2[4 * k + 1] * S);
        pv.z = exp2f(An2[4 * k + 2] * S); pv.w = exp2f(An2[4 * k + 3] * S);
        hv.x = h[4 * k + 0]; hv.y = h[4 * k + 1];
        hv.z = h[4 * k + 2]; hv.w = h[4 * k + 3];
        *(float4*)(P + o + 4 * k)  = pv;
        *(float4*)(hp + o + 4 * k) = hv;
    }
}

// ---- scan pass 2: serial combine over chunks ----
__global__ void scan_combine_kernel(const float* __restrict__ P, float* __restrict__ hp) {
    long g = (long)blockIdx.x * 256 + threadIdx.x;
    int b = (int)(g / ((long)DI * 16));
    long rem = g - (long)b * DI * 16;
    float h = 0.f;
    for (int q = 0; q < NC; q++) {
        long o = ((long)(b * NC + q)) * (DI * 16) + rem;
        float Pv = P[o], hv = hp[o];
        hp[o] = h;
        h = fmaf(Pv, h, hv);
    }
}

// ---- scan pass 3: re-run chunk from h_in, emit gated y ----
__global__ __launch_bounds__(256)
void scan_emit_kernel(const float* __restrict__ dbc, const float* __restrict__ xc,
                      float* __restrict__ xz,
                      const float* __restrict__ A_log, const float* __restrict__ dt_W,
                      const float* __restrict__ dt_b, const float* __restrict__ Dv,
                      const float* __restrict__ hin) {
    __shared__ float sdt[LC];
    __shared__ float sB[LC][16];
    __shared__ float sC[LC][16];
    int tid = threadIdx.x;
    int cg = blockIdx.x % CGD;
    int bq = blockIdx.x / CGD;
    int b = bq / NC, q = bq % NC;
    int c = cg * 256 + tid;
    long row0 = (long)b * L_SEQ + q * LC;

    for (int idx = tid; idx < LC * 33; idx += 256) {
        int r = idx / 33, j = idx - r * 33;
        float v = dbc[row0 * 33 + idx];
        if (j == 0)      sdt[r] = v;
        else if (j < 17) sB[r][j - 1] = v;
        else             sC[r][j - 17] = v;
    }

    float dtw = dt_W[c], dtb = dt_b[c], Dc = Dv[c];
    float An2[16];
    {
        const float4* ap = (const float4*)(A_log + c * 16);
#pragma unroll
        for (int k = 0; k < 4; k++) {
            float4 a = ap[k];
            An2[4 * k + 0] = -__expf(a.x) * LOG2E; An2[4 * k + 1] = -__expf(a.y) * LOG2E;
            An2[4 * k + 2] = -__expf(a.z) * LOG2E; An2[4 * k + 3] = -__expf(a.w) * LOG2E;
        }
    }
    float h[16];
    {
        long o = ((long)bq * DI + c) * 16;
#pragma unroll
        for (int k = 0; k < 4; k++) {
            float4 hv = *(const float4*)(hin + o + 4 * k);
            h[4 * k + 0] = hv.x; h[4 * k + 1] = hv.y;
            h[4 * k + 2] = hv.z; h[4 * k + 3] = hv.w;
        }
    }
    __syncthreads();

    for (int rr = 0; rr < LC; rr += 8) {
        float xv[8], zv[8];
#pragma unroll
        for (int u = 0; u < 8; u++) xv[u] = xc[(row0 + rr + u) * DI + c];
#pragma unroll
        for (int u = 0; u < 8; u++) zv[u] = xz[(row0 + rr + u) * 2 * DI + DI + c];
#pragma unroll
        for (int u = 0; u < 8; u++) {
            int r = rr + u;
            float dt = softplus_fast(fmaf(sdt[r], dtw, dtb));
            float bb[16], cc[16];
            *(float4*)(bb + 0)  = *(const float4*)&sB[r][0];
            *(float4*)(bb + 4)  = *(const float4*)&sB[r][4];
            *(float4*)(bb + 8)  = *(const float4*)&sB[r][8];
            *(float4*)(bb + 12) = *(const float4*)&sB[r][12];
            *(float4*)(cc + 0)  = *(const float4*)&sC[r][0];
            *(float4*)(cc + 4)  = *(const float4*)&sC[r][4];
            *(float4*)(cc + 8)  = *(const float4*)&sC[r][8];
            *(float4*)(cc + 12) = *(const float4*)&sC[r][12];
            float g = dt * xv[u];
            float y0 = 0.f, y1 = 0.f, y2 = 0.f, y3 = 0.f;
#pragma unroll
            for (int n = 0; n < 4; n++) {
                float a0 = exp2f(dt * An2[4 * n + 0]);
                float a1 = exp2f(dt * An2[4 * n + 1]);
                float a2 = exp2f(dt * An2[4 * n + 2]);
                float a3 = exp2f(dt * An2[4 * n + 3]);
                h[4 * n + 0] = fmaf(a0, h[4 * n + 0], g * bb[4 * n + 0]);
                h[4 * n + 1] = fmaf(a1, h[4 * n + 1], g * bb[4 * n + 1]);
                h[4 * n + 2] = fmaf(a2, h[4 * n + 2], g * bb[4 * n + 2]);
                h[4 * n + 3] = fmaf(a3, h[4 * n + 3], g * bb[4 * n + 3]);
                y0 = fmaf(h[4 * n + 0], cc[4 * n + 0], y0);
                y1 = fmaf(h[4 * n + 1], cc[4 * n + 1], y1);
                y2 = fmaf(h[4 * n + 2], cc[4 * n + 2], y2);
                y3 = fmaf(h[4 * n + 3], cc[4 * n + 3], y3);
            }
            float y = (y0 + y1) + (y2 + y3);
            y = (y + xv[u] * Dc) * silu_fast(zv[u]);
            xz[(row0 + r) * 2 * DI + c] = y;
        }
    }
}

// ---- rmsnorm over y (stride-2*DI rows) -> bf16 yn ----
__global__ void rmsnorm_y_kernel(const float* __restrict__ xz, const float* __restrict__ w,
                                 short* __restrict__ yn) {
    __shared__ float sh[8];
    int row = blockIdx.x;
    const float* yr = xz + (long)row * 2 * DI;
    float v[6];
    float ss = 0.f;
#pragma unroll
    for (int i = 0; i < 6; i++) {
        v[i] = yr[threadIdx.x + 256 * i];
        ss += v[i] * v[i];
    }
    ss = blockReduceSum(ss, sh);
    float r = rsqrtf(ss / DI + 1e-6f);
#pragma unroll
    for (int i = 0; i < 6; i++)
        yn[(long)row * DI + threadIdx.x + 256 * i] = f2bf(v[i] * r * w[threadIdx.x + 256 * i]);
}

extern "C" void kernel_launch(void* const* d_in, const int* in_sizes, int n_in,
                              void* d_out, int out_size, void* d_ws, size_t ws_size,
                              hipStream_t stream) {
    const float* x          = (const float*)d_in[0];
    const float* norm_w     = (const float*)d_in[1];
    const float* inp_norm_w = (const float*)d_in[2];
    const float* inp_W      = (const float*)d_in[3];
    const float* conv_w     = (const float*)d_in[4];
    const float* conv_b     = (const float*)d_in[5];
    const float* xproj_W    = (const float*)d_in[6];
    const float* dt_W       = (const float*)d_in[7];
    const float* dt_b       = (const float*)d_in[8];
    const float* A_log      = (const float*)d_in[9];
    const float* Dv         = (const float*)d_in[10];
    const float* out_norm_w = (const float*)d_in[11];
    const float* out_W      = (const float*)d_in[12];
    float* out = (float*)d_out;

    float* ws  = (float*)d_ws;
    float* xz  = ws;                         // NROWS*2*DI fp32
    float* xc  = xz + (long)NROWS * 2 * DI;  // NROWS*DI fp32 (conv out)
    float* dbc = xc + (long)NROWS * DI;      // NROWS*33
    float* scal = dbc + (long)NROWS * 33;    // 2
    float* part = scal + 2;                  // 2048
    float* Pbuf = part + 2048;               // B*NC*DI*16 fp32  (Wq1 overlaid pre-scan)
    float* hp   = Pbuf + (long)B_SZ * NC * DI * 16;
    short* Wq2  = (short*)(hp + (long)B_SZ * NC * DI * 16);  // DM*DI bf16

    short* A1  = (short*)xc;     // NROWS*DM bf16, dead before conv writes xc
    short* Wq1 = (short*)Pbuf;   // 2*DI*DM bf16, dead before scan_part writes Pbuf
    short* Yn  = (short*)xc;     // NROWS*DI bf16, written after xc is consumed

    rmsnorm2_kernel<<<NROWS, 256, 0, stream>>>(x, norm_w, inp_norm_w, A1);
    abssum_partial_kernel<<<1024, 256, 0, stream>>>(inp_W, 2 * DI * DM, part);
    reduce_partials_kernel<<<1, 512, 0, stream>>>(part, scal);
    abssum_partial_kernel<<<1024, 256, 0, stream>>>(out_W, DM * DI, part + 1024);
    reduce_partials_kernel<<<1, 512, 0, stream>>>(part + 1024, scal + 1);
    quant_bf16_kernel<<<(2 * DI * DM + 255) / 256, 256, 0, stream>>>(
        inp_W, 2 * DI * DM, scal, 1.f / (2 * DI * DM), Wq1);
    quant_bf16_kernel<<<(DM * DI + 255) / 256, 256, 0, stream>>>(
        out_W, DM * DI, scal + 1, 1.f / (DM * DI), Wq2);

    gemm_mfma_kernel<<<dim3(2 * DI / 128, NROWS / 128), 256, 0, stream>>>(
        A1, Wq1, nullptr, xz, NROWS, 2 * DI, DM, scal, 1.f / (2 * DI * DM));
    conv_silu_kernel<<<(NROWS * DI + 255) / 256, 256, 0, stream>>>(xz, conv_w, conv_b, xc);
    xproj_kernel<<<NROWS, 64, 0, stream>>>(xc, xproj_W, dbc);

    scan_part_kernel<<<B_SZ * NC * CGD, 256, 0, stream>>>(dbc, xc, A_log, dt_W, dt_b, Pbuf, hp);
    scan_combine_kernel<<<(B_SZ * DI * 16) / 256, 256, 0, stream>>>(Pbuf, hp);
    scan_emit_kernel<<<B_SZ * NC * CGD, 256, 0, stream>>>(dbc, xc, xz, A_log, dt_W, dt_b, Dv, hp);

    rmsnorm_y_kernel<<<NROWS, 256, 0, stream>>>(xz, out_norm_w, Yn);
    gemm_mfma_kernel<<<dim3(DM / 128, NROWS / 128), 256, 0, stream>>>(
        Yn, Wq2, x, out, NROWS, DM, DI, scal + 1, 1.f / (DM * DI));
}